// Round 9
// baseline (238.899 us; speedup 1.0000x reference)
//
#include <hip/hip_runtime.h>

#define Bn 512
#define Tn 1024
#define Nn 64
#define WB 4      // waves per batch: 64 segments, wave h owns columns m = 16h+n
#define BURN 16   // burn-in steps (verified: R3 scalar + R6/R7/R8 MFMA, absmax 0.0)

typedef float    f4  __attribute__((ext_vector_type(4)));
typedef __fp16   pk2 __attribute__((ext_vector_type(2)));   // cvt_pkrtz result type
typedef __fp16   pk4 __attribute__((ext_vector_type(4)));
typedef __fp16   pk8 __attribute__((ext_vector_type(8)));
typedef _Float16 h8v __attribute__((ext_vector_type(8)));

__device__ __forceinline__ float wave_sum(float v) {
#pragma unroll
    for (int off = 32; off >= 1; off >>= 1) v += __shfl_xor(v, off, 64);
    return v;
}

// One wave = 16 segments (MFMA columns) of batch b; WB=4 waves cover the
// 64 segments of one batch. U' = E^T diag-scaled P, 8 mfma/step, no LDS
// (B k-map chosen == C/D layout so B packs in-register; A uses same k-map,
// contraction invariant). Depth-8 register ring prefetches emit rows.
//
// __launch_bounds__(64, 2): the ring needs 8 slots x 16 floats = 128 VGPR by
// itself (+A 32, +U 16, +misc) ~ 210 total. R8 compiled WITHOUT the min-waves
// clause allocated only 128 VGPRs and sank the refill loads toward their
// consumers (loads are side-effect-free), collapsing the prefetch distance to
// ~1 step -> 79% memory stall (VALUBusy 21%, 6500 cy/step). Declaring 2
// waves/EU raises the cap to 256 VGPR -- matching the occupancy we actually
// achieve (grid = 2048 blocks = 8 waves/CU = one residency round) -- so the
// ring stays register-resident and loads issue ~8 steps (~2000 cy) early.
// (Inverse of the R1 lesson: there min_waves=8 crushed the budget to 32 and
// spilled; the clause must DECLARE reality, not wish for more.)
__global__ __launch_bounds__(64, 2) void crf_mfma(
    const float* __restrict__ emit,
    const int*   __restrict__ target,
    const int*   __restrict__ mask,
    const float* __restrict__ trans,
    const float* __restrict__ strans,
    const float* __restrict__ etrans,
    float*       __restrict__ out)
{
    const int lane = threadIdx.x;
    const int n = lane & 15;          // column within this wave's MFMA
    const int g = lane >> 4;          // lane group
    const int b = blockIdx.x & (Bn - 1);
    const int h = blockIdx.x >> 9;    // 0..3
    const int m = 16 * h + n;         // global segment id, 0..63
    const size_t ebase = (size_t)b * Tn * Nn;

    // ---- A fragments with k-map k = 32hh + 16*(j>>2) + 4g + (j&3)
    // Et[row][k] = exp(trans[k][row]); row = 16r + n
    h8v A[4][2];
#pragma unroll
    for (int r = 0; r < 4; ++r)
#pragma unroll
        for (int hh = 0; hh < 2; ++hh) {
            h8v a;
#pragma unroll
            for (int j = 0; j < 8; ++j) {
                int kk = 32 * hh + 16 * (j >> 2) + 4 * g + (j & 3);
                a[j] = (_Float16)__expf(trans[kk * Nn + 16 * r + n]);
            }
            A[r][hh] = a;
        }

    // ---- len = popcount of prefix mask
    const int* mrow = mask + (size_t)b * Tn;
    int lsum = 0;
#pragma unroll
    for (int k = 0; k < Tn / Nn; ++k) lsum += mrow[k * Nn + lane];
#pragma unroll
    for (int off = 32; off >= 1; off >>= 1) lsum += __shfl_xor(lsum, off, 64);
    const int len = lsum;                       // in [512, 1024]

    // ---- segment bounds for column m
    const int a0v   = (m * len) >> 6;
    const int a1v   = ((m + 1) * len) >> 6;
    int start = a0v - BURN; if (start < 1) start = 1;   // start==1 -> exact prefix
    const int tendv = a1v - 1;                  // last step t for this column
    const int maxk  = ((len + 63) >> 6) + BURN; // covers all columns' records

    // ---- end weights: only global segment 63 weights its final colsum
    float wsel[4][4];
#pragma unroll
    for (int r = 0; r < 4; ++r) {
        f4 ee = *(const f4*)(emit + ebase + (size_t)(len - 1) * Nn + 16 * r + 4 * g);
        f4 et = *(const f4*)(etrans + 16 * r + 4 * g);
#pragma unroll
        for (int c = 0; c < 4; ++c)
            wsel[r][c] = (m == 63) ? __expf(ee[c] + et[c]) : 1.0f;
    }

    // ---- U init (C/D layout: row = 16r + 4g + c, col n) = u_{start-1}.
    // start==1 (m==0 or clamped early segment): exact u_0 = exp(strans).
    float U[4][4];
#pragma unroll
    for (int r = 0; r < 4; ++r) {
        f4 st = *(const f4*)(strans + 16 * r + 4 * g);
#pragma unroll
        for (int c = 0; c < 4; ++c)
            U[r][c] = (start == 1) ? __expf(st[c]) : 1.0f;
    }

    int   S = 0;
    float L0 = 0.0f, contrib = 0.0f;

    // ---- depth-8 prefetch ring: rbuf[q] holds raw emit row (start + 8*kb + q - 1)
    f4 rbuf[8][4];
#pragma unroll
    for (int d = 0; d < 8; ++d) {
        int tr = start - 1 + d; if (tr > Tn - 1) tr = Tn - 1;
        const f4* p = (const f4*)(emit + ebase + (size_t)tr * Nn);
#pragma unroll
        for (int r = 0; r < 4; ++r) rbuf[d][r] = p[4 * r + g];
    }

    const f4 zero4 = {0.f, 0.f, 0.f, 0.f};
    const int nkb = (maxk + 7) >> 3;            // extra steps harmless:
                                                // rescale bounds U, records latch on ==

    for (int kb = 0; kb < nkb; ++kb) {
#pragma unroll
        for (int q = 0; q < 8; ++q) {
            const int k = 8 * kb + q;

            // W for this step (row start+k-1), then refill slot q (row start+k+7)
            float Wx[4][4];
#pragma unroll
            for (int r = 0; r < 4; ++r)
#pragma unroll
                for (int c = 0; c < 4; ++c) Wx[r][c] = __expf(rbuf[q][r][c]);
            {
                int tr = start + k + 7; if (tr > Tn - 1) tr = Tn - 1;
                const f4* p = (const f4*)(emit + ebase + (size_t)tr * Nn);
#pragma unroll
                for (int r = 0; r < 4; ++r) rbuf[q][r] = p[4 * r + g];
            }

            // burn-in end: U = u_{a0v-1}; record L0, reset S (per-column k!)
            bool br = m && ((start + k) == a0v);
            if (__any(br)) {
                float cs = 0.f;
#pragma unroll
                for (int r = 0; r < 4; ++r)
#pragma unroll
                    for (int c = 0; c < 4; ++c) cs += U[r][c];
                cs += __shfl_xor(cs, 16, 64);
                cs += __shfl_xor(cs, 32, 64);
                float l0v = __logf(cs);
                if (br) { L0 = l0v; S = 0; }
            }

            // per-column rescale: mx = col max -> mx*2^mk in [1,2)
            float m0 = fmaxf(fmaxf(U[0][0], U[0][1]), fmaxf(U[0][2], U[0][3]));
            float m1 = fmaxf(fmaxf(U[1][0], U[1][1]), fmaxf(U[1][2], U[1][3]));
            float m2 = fmaxf(fmaxf(U[2][0], U[2][1]), fmaxf(U[2][2], U[2][3]));
            float m3 = fmaxf(fmaxf(U[3][0], U[3][1]), fmaxf(U[3][2], U[3][3]));
            float mx = fmaxf(fmaxf(m0, m1), fmaxf(m2, m3));
            mx = fmaxf(mx, __shfl_xor(mx, 16, 64));
            mx = fmaxf(mx, __shfl_xor(mx, 32, 64));
            const int mk = 127 - ((__float_as_int(mx) >> 23) & 0xff);
            S += mk;
            const float sc2 = __int_as_float((127 + mk) << 23);   // 2^mk

            // p = U * 2^mk * W -> fp16, packed in-register as B (k-map above)
            float P_[4][4];
#pragma unroll
            for (int r = 0; r < 4; ++r)
#pragma unroll
                for (int c = 0; c < 4; ++c) P_[r][c] = U[r][c] * sc2 * Wx[r][c];

            pk2 c00 = __builtin_amdgcn_cvt_pkrtz(P_[0][0], P_[0][1]);
            pk2 c01 = __builtin_amdgcn_cvt_pkrtz(P_[0][2], P_[0][3]);
            pk2 c10 = __builtin_amdgcn_cvt_pkrtz(P_[1][0], P_[1][1]);
            pk2 c11 = __builtin_amdgcn_cvt_pkrtz(P_[1][2], P_[1][3]);
            pk2 c20 = __builtin_amdgcn_cvt_pkrtz(P_[2][0], P_[2][1]);
            pk2 c21 = __builtin_amdgcn_cvt_pkrtz(P_[2][2], P_[2][3]);
            pk2 c30 = __builtin_amdgcn_cvt_pkrtz(P_[3][0], P_[3][1]);
            pk2 c31 = __builtin_amdgcn_cvt_pkrtz(P_[3][2], P_[3][3]);
            pk4 b0lo = __builtin_shufflevector(c00, c01, 0, 1, 2, 3);
            pk4 b0hi = __builtin_shufflevector(c10, c11, 0, 1, 2, 3);
            pk4 b1lo = __builtin_shufflevector(c20, c21, 0, 1, 2, 3);
            pk4 b1hi = __builtin_shufflevector(c30, c31, 0, 1, 2, 3);
            pk8 b0p = __builtin_shufflevector(b0lo, b0hi, 0, 1, 2, 3, 4, 5, 6, 7);
            pk8 b1p = __builtin_shufflevector(b1lo, b1hi, 0, 1, 2, 3, 4, 5, 6, 7);
            h8v B0 = __builtin_bit_cast(h8v, b0p);
            h8v B1 = __builtin_bit_cast(h8v, b1p);

            // U' = Et x P  (8 MFMA, no LDS anywhere)
#pragma unroll
            for (int r = 0; r < 4; ++r) {
                f4 acc = __builtin_amdgcn_mfma_f32_16x16x32_f16(A[r][0], B0, zero4, 0, 0, 0);
                acc     = __builtin_amdgcn_mfma_f32_16x16x32_f16(A[r][1], B1, acc,   0, 0, 0);
#pragma unroll
                for (int c = 0; c < 4; ++c) U[r][c] = acc[c];
            }

            // segment-end record (fires on ~2-3 iterations total)
            bool rec = (start + k) == tendv;
            if (__any(rec)) {
                float cs = 0.f;
#pragma unroll
                for (int r = 0; r < 4; ++r)
#pragma unroll
                    for (int c = 0; c < 4; ++c) cs = fmaf(U[r][c], wsel[r][c], cs);
                cs += __shfl_xor(cs, 16, 64);
                cs += __shfl_xor(cs, 32, 64);
                float lv = __logf(cs);
                if (rec) contrib = lv - (float)S * 0.6931471805599453f - L0;
            }
        }
    }

    // 4 lanes per column hold identical contrib -> /4
    float tot = wave_sum(contrib) * 0.25f;

    // ---- gold-path score: computed once per batch, by wave h==0
    float sc = 0.0f;
    const int* trow = target + (size_t)b * Tn;
    if (h == 0) {
#pragma unroll
        for (int k = 0; k < Tn / Nn; ++k) {
            int t = k * Nn + lane;
            if (t < len) {
                int gT = trow[t];
                sc += emit[ebase + (size_t)t * Nn + gT];
                if (t > 0) sc += trans[trow[t - 1] * Nn + gT];
            }
        }
        sc = wave_sum(sc);
    }

    if (lane == 0) {
        float add = tot;
        if (h == 0) add -= sc + strans[trow[0]] + etrans[trow[len - 1]];
        atomicAdd(out, add * (1.0f / (float)Bn));
    }
}

extern "C" void kernel_launch(void* const* d_in, const int* in_sizes, int n_in,
                              void* d_out, int out_size, void* d_ws, size_t ws_size,
                              hipStream_t stream) {
    const float* emit   = (const float*)d_in[0];
    const int*   target = (const int*)d_in[1];
    const int*   mask   = (const int*)d_in[2];
    const float* trans  = (const float*)d_in[3];
    const float* strans = (const float*)d_in[4];
    const float* etrans = (const float*)d_in[5];
    float* out = (float*)d_out;

    (void)hipMemsetAsync(out, 0, sizeof(float), stream);
    crf_mfma<<<Bn * WB, Nn, 0, stream>>>(emit, target, mask, trans, strans, etrans, out);
}

// Round 10
// 228.238 us; speedup vs baseline: 1.0467x; 1.0467x over previous
//
#include <hip/hip_runtime.h>

#define Bn 512
#define Tn 1024
#define Nn 64
#define WB 4      // waves per batch: 64 segments, wave h owns columns m = 16h+n
#define BURN 16   // burn-in steps (verified: R3 scalar + R6/R7/R8/R9 MFMA, absmax 0.0)
#define NBUF 4    // LDS stage ring: 4 buffers x 4KB (one step's 16 rows each)

typedef float    f4  __attribute__((ext_vector_type(4)));
typedef __fp16   pk2 __attribute__((ext_vector_type(2)));   // cvt_pkrtz result type
typedef __fp16   pk4 __attribute__((ext_vector_type(4)));
typedef __fp16   pk8 __attribute__((ext_vector_type(8)));
typedef _Float16 h8v __attribute__((ext_vector_type(8)));

typedef __attribute__((address_space(1))) void as1_void;
typedef __attribute__((address_space(3))) void as3_void;

// Direct global->LDS DMA, 16B per lane. LDS dest = uniform base + 16*lane.
// Integer round-trip casts are the shipped idiom (CK amd_direct_load):
// generic->AS1 is VA-identical; generic LDS VA's low 32 bits are the offset.
__device__ __forceinline__ void stage16(const float* g, float* l) {
    __builtin_amdgcn_global_load_lds((as1_void*)(unsigned long long)g,
                                     (as3_void*)(unsigned long long)l, 16, 0, 0);
}

#define VMCNT(N) asm volatile("s_waitcnt vmcnt(" #N ")" ::: "memory")

__device__ __forceinline__ float wave_sum(float v) {
#pragma unroll
    for (int off = 32; off >= 1; off >>= 1) v += __shfl_xor(v, off, 64);
    return v;
}

// One wave = 16 segments (MFMA columns) of batch b; WB=4 waves cover the 64
// segments. U' = E^T diag-scaled P, 8 mfma/step, B packed in-register (k-map
// == C/D layout, A loaded with same k-map -> contraction invariant).
//
// Emit rows are staged via global_load_lds into a 4-buffer LDS ring with
// COUNTED vmcnt (never 0 in the loop): stage k+3 is issued each step, then
// s_waitcnt vmcnt(12) guarantees buffer k landed while 3 stages stay in
// flight. R8/R9 proved the compiler will not hold a register prefetch ring
// (it sinks side-effect-free loads toward consumers regardless of
// launch_bounds; VGPR cap != schedule target) -> prefetch depth now lives in
// the DMA queue, which the scheduler cannot collapse: the builtin has side
// effects and is pinned between "memory"-clobbered waitcnts.
// Layout: stage inst r, lane l=(16g+n) writes LDS float r*256+4l from its own
// column's row tr_n floats [16r+4g..+4) -> read-back lane(n,g) quad r at
// float 256r+64g+4n is its own data; both sides bank-conflict-free.
__global__ __launch_bounds__(64) void crf_mfma(
    const float* __restrict__ emit,
    const int*   __restrict__ target,
    const int*   __restrict__ mask,
    const float* __restrict__ trans,
    const float* __restrict__ strans,
    const float* __restrict__ etrans,
    float*       __restrict__ out)
{
    __shared__ __align__(16) float sbuf[NBUF * 1024];   // 16 KB

    const int lane = threadIdx.x;
    const int n = lane & 15;          // column within this wave's MFMA
    const int g = lane >> 4;          // lane group
    const int b = blockIdx.x & (Bn - 1);
    const int h = blockIdx.x >> 9;    // 0..3
    const int m = 16 * h + n;         // global segment id, 0..63
    const size_t ebase = (size_t)b * Tn * Nn;

    // ---- A fragments with k-map k = 32hh + 16*(j>>2) + 4g + (j&3)
    h8v A[4][2];
#pragma unroll
    for (int r = 0; r < 4; ++r)
#pragma unroll
        for (int hh = 0; hh < 2; ++hh) {
            h8v a;
#pragma unroll
            for (int j = 0; j < 8; ++j) {
                int kk = 32 * hh + 16 * (j >> 2) + 4 * g + (j & 3);
                a[j] = (_Float16)__expf(trans[kk * Nn + 16 * r + n]);
            }
            A[r][hh] = a;
        }

    // ---- len = popcount of prefix mask
    const int* mrow = mask + (size_t)b * Tn;
    int lsum = 0;
#pragma unroll
    for (int k = 0; k < Tn / Nn; ++k) lsum += mrow[k * Nn + lane];
#pragma unroll
    for (int off = 32; off >= 1; off >>= 1) lsum += __shfl_xor(lsum, off, 64);
    const int len = lsum;                       // in [512, 1024]

    // ---- segment bounds for column m
    const int a0v   = (m * len) >> 6;
    const int a1v   = ((m + 1) * len) >> 6;
    int start = a0v - BURN; if (start < 1) start = 1;   // start==1 -> exact prefix
    const int tendv = a1v - 1;                  // last step t for this column
    const int maxk  = ((len + 63) >> 6) + BURN; // covers all columns' records

    // ---- end weights: only global segment 63 weights its final colsum
    float wsel[4][4];
#pragma unroll
    for (int r = 0; r < 4; ++r) {
        f4 ee = *(const f4*)(emit + ebase + (size_t)(len - 1) * Nn + 16 * r + 4 * g);
        f4 et = *(const f4*)(etrans + 16 * r + 4 * g);
#pragma unroll
        for (int c = 0; c < 4; ++c)
            wsel[r][c] = (m == 63) ? __expf(ee[c] + et[c]) : 1.0f;
    }

    // ---- U init (C/D layout: row = 16r + 4g + c, col n) = u_{start-1}.
    float U[4][4];
#pragma unroll
    for (int r = 0; r < 4; ++r) {
        f4 st = *(const f4*)(strans + 16 * r + 4 * g);
#pragma unroll
        for (int c = 0; c < 4; ++c)
            U[r][c] = (start == 1) ? __expf(st[c]) : 1.0f;
    }

    int   S = 0;
    float L0 = 0.0f, contrib = 0.0f;

    // stage one step-tile (16 rows) into buffer bf: 4 x global_load_lds.
    // Per-lane source row tr_n = start_n + kstep - 1 (clamped); lane offset 4g.
    auto stage = [&](int bf, int kstep) {
        int tr = start + kstep - 1; if (tr > Tn - 1) tr = Tn - 1;
        const float* gs = emit + ebase + (size_t)tr * Nn + 4 * g;
        float* ls = sbuf + bf * 1024;
#pragma unroll
        for (int r = 0; r < 4; ++r)
            stage16(gs + 16 * r, ls + 256 * r);
    };

    // isolate our vmcnt counting from prologue loads, then prime 3 buffers
    VMCNT(0);
    stage(0, 0); stage(1, 1); stage(2, 2);      // 12 outstanding

    const f4 zero4 = {0.f, 0.f, 0.f, 0.f};
    const int nkb = (maxk + 3) >> 2;            // extra steps harmless:
                                                // rescale bounds U, records latch on ==

    for (int kb = 0; kb < nkb; ++kb) {
#pragma unroll
        for (int q = 0; q < 4; ++q) {
            const int k = 4 * kb + q;

            stage((q + 3) & 3, k + 3);          // 16 outstanding
            VMCNT(12);                          // oldest stage (step k) landed
            __builtin_amdgcn_sched_barrier(0);

            // this step's emit row quads from buffer q (conflict-free b128)
            const float* sb = sbuf + q * 1024 + 64 * g + 4 * n;
            f4 w0 = *(const f4*)(sb);
            f4 w1 = *(const f4*)(sb + 256);
            f4 w2 = *(const f4*)(sb + 512);
            f4 w3 = *(const f4*)(sb + 768);
            float Wx[4][4];
#pragma unroll
            for (int c = 0; c < 4; ++c) {
                Wx[0][c] = __expf(w0[c]);
                Wx[1][c] = __expf(w1[c]);
                Wx[2][c] = __expf(w2[c]);
                Wx[3][c] = __expf(w3[c]);
            }

            // burn-in end: U = u_{a0v-1}; record L0, reset S (per-column k!)
            bool br = m && ((start + k) == a0v);
            if (__any(br)) {
                float cs = 0.f;
#pragma unroll
                for (int r = 0; r < 4; ++r)
#pragma unroll
                    for (int c = 0; c < 4; ++c) cs += U[r][c];
                cs += __shfl_xor(cs, 16, 64);
                cs += __shfl_xor(cs, 32, 64);
                float l0v = __logf(cs);
                if (br) { L0 = l0v; S = 0; }
            }

            // per-column rescale: mx = col max -> mx*2^mk in [1,2)
            float m0 = fmaxf(fmaxf(U[0][0], U[0][1]), fmaxf(U[0][2], U[0][3]));
            float m1 = fmaxf(fmaxf(U[1][0], U[1][1]), fmaxf(U[1][2], U[1][3]));
            float m2 = fmaxf(fmaxf(U[2][0], U[2][1]), fmaxf(U[2][2], U[2][3]));
            float m3 = fmaxf(fmaxf(U[3][0], U[3][1]), fmaxf(U[3][2], U[3][3]));
            float mx = fmaxf(fmaxf(m0, m1), fmaxf(m2, m3));
            mx = fmaxf(mx, __shfl_xor(mx, 16, 64));
            mx = fmaxf(mx, __shfl_xor(mx, 32, 64));
            const int mk = 127 - ((__float_as_int(mx) >> 23) & 0xff);
            S += mk;
            const float sc2 = __int_as_float((127 + mk) << 23);   // 2^mk

            // p = U * 2^mk * W -> fp16, packed in-register as B (k-map above)
            float P_[4][4];
#pragma unroll
            for (int r = 0; r < 4; ++r)
#pragma unroll
                for (int c = 0; c < 4; ++c) P_[r][c] = U[r][c] * sc2 * Wx[r][c];

            pk2 c00 = __builtin_amdgcn_cvt_pkrtz(P_[0][0], P_[0][1]);
            pk2 c01 = __builtin_amdgcn_cvt_pkrtz(P_[0][2], P_[0][3]);
            pk2 c10 = __builtin_amdgcn_cvt_pkrtz(P_[1][0], P_[1][1]);
            pk2 c11 = __builtin_amdgcn_cvt_pkrtz(P_[1][2], P_[1][3]);
            pk2 c20 = __builtin_amdgcn_cvt_pkrtz(P_[2][0], P_[2][1]);
            pk2 c21 = __builtin_amdgcn_cvt_pkrtz(P_[2][2], P_[2][3]);
            pk2 c30 = __builtin_amdgcn_cvt_pkrtz(P_[3][0], P_[3][1]);
            pk2 c31 = __builtin_amdgcn_cvt_pkrtz(P_[3][2], P_[3][3]);
            pk4 b0lo = __builtin_shufflevector(c00, c01, 0, 1, 2, 3);
            pk4 b0hi = __builtin_shufflevector(c10, c11, 0, 1, 2, 3);
            pk4 b1lo = __builtin_shufflevector(c20, c21, 0, 1, 2, 3);
            pk4 b1hi = __builtin_shufflevector(c30, c31, 0, 1, 2, 3);
            pk8 b0p = __builtin_shufflevector(b0lo, b0hi, 0, 1, 2, 3, 4, 5, 6, 7);
            pk8 b1p = __builtin_shufflevector(b1lo, b1hi, 0, 1, 2, 3, 4, 5, 6, 7);
            h8v B0 = __builtin_bit_cast(h8v, b0p);
            h8v B1 = __builtin_bit_cast(h8v, b1p);

            // U' = Et x P  (8 MFMA)
#pragma unroll
            for (int r = 0; r < 4; ++r) {
                f4 acc = __builtin_amdgcn_mfma_f32_16x16x32_f16(A[r][0], B0, zero4, 0, 0, 0);
                acc     = __builtin_amdgcn_mfma_f32_16x16x32_f16(A[r][1], B1, acc,   0, 0, 0);
#pragma unroll
                for (int c = 0; c < 4; ++c) U[r][c] = acc[c];
            }

            // segment-end record (fires on ~2-3 iterations total)
            bool rec = (start + k) == tendv;
            if (__any(rec)) {
                float cs = 0.f;
#pragma unroll
                for (int r = 0; r < 4; ++r)
#pragma unroll
                    for (int c = 0; c < 4; ++c) cs = fmaf(U[r][c], wsel[r][c], cs);
                cs += __shfl_xor(cs, 16, 64);
                cs += __shfl_xor(cs, 32, 64);
                float lv = __logf(cs);
                if (rec) contrib = lv - (float)S * 0.6931471805599453f - L0;
            }
        }
    }
    VMCNT(0);   // drain tail stages (LDS writes only; buffers dead)

    // 4 lanes per column hold identical contrib -> /4
    float tot = wave_sum(contrib) * 0.25f;

    // ---- gold-path score: computed once per batch, by wave h==0
    float sc = 0.0f;
    const int* trow = target + (size_t)b * Tn;
    if (h == 0) {
#pragma unroll
        for (int k = 0; k < Tn / Nn; ++k) {
            int t = k * Nn + lane;
            if (t < len) {
                int gT = trow[t];
                sc += emit[ebase + (size_t)t * Nn + gT];
                if (t > 0) sc += trans[trow[t - 1] * Nn + gT];
            }
        }
        sc = wave_sum(sc);
    }

    if (lane == 0) {
        float add = tot;
        if (h == 0) add -= sc + strans[trow[0]] + etrans[trow[len - 1]];
        atomicAdd(out, add * (1.0f / (float)Bn));
    }
}

extern "C" void kernel_launch(void* const* d_in, const int* in_sizes, int n_in,
                              void* d_out, int out_size, void* d_ws, size_t ws_size,
                              hipStream_t stream) {
    const float* emit   = (const float*)d_in[0];
    const int*   target = (const int*)d_in[1];
    const int*   mask   = (const int*)d_in[2];
    const float* trans  = (const float*)d_in[3];
    const float* strans = (const float*)d_in[4];
    const float* etrans = (const float*)d_in[5];
    float* out = (float*)d_out;

    (void)hipMemsetAsync(out, 0, sizeof(float), stream);
    crf_mfma<<<Bn * WB, Nn, 0, stream>>>(emit, target, mask, trans, strans, etrans, out);
}

// Round 11
// 226.157 us; speedup vs baseline: 1.0563x; 1.0092x over previous
//
#include <hip/hip_runtime.h>

#define Bn 512
#define Tn 1024
#define Nn 64
#define BURN 16   // burn-in steps (verified: R3 scalar + R6-R10 MFMA, absmax 0.0)
#define NBUF 3    // LDS group ring: 3 x 16KB (one 4-step group each)

typedef float    f4  __attribute__((ext_vector_type(4)));
typedef __fp16   pk2 __attribute__((ext_vector_type(2)));   // cvt_pkrtz result type
typedef __fp16   pk4 __attribute__((ext_vector_type(4)));
typedef __fp16   pk8 __attribute__((ext_vector_type(8)));
typedef _Float16 h8v __attribute__((ext_vector_type(8)));

typedef __attribute__((address_space(1))) void as1_void;
typedef __attribute__((address_space(3))) void as3_void;

// Direct global->LDS DMA, 16B/lane, LDS dest = uniform base + 16*lane.
__device__ __forceinline__ void stage16(const float* g, float* l) {
    __builtin_amdgcn_global_load_lds((as1_void*)(unsigned long long)g,
                                     (as3_void*)(unsigned long long)l, 16, 0, 0);
}
#define VMCNT(N) asm volatile("s_waitcnt vmcnt(" #N ")" ::: "memory")

__device__ __forceinline__ float wave_sum(float v) {
#pragma unroll
    for (int off = 32; off >= 1; off >>= 1) v += __shfl_xor(v, off, 64);
    return v;
}

// One wave = one batch b, its 16 segments = 16 MFMA columns (R7 geometry:
// fewest total bytes). U' = E^T diag-scaled P, 8 mfma/step, B packed
// in-register (k-map == C/D layout; A uses same k-map -> contraction
// invariant). Step math is bit-identical to the R10-verified kernel.
//
// STAGING IS COALESCED BY COLUMN (the R8/R9/R10 fix): each global_load_lds
// reads 1KB CONTIGUOUS -- 4 consecutive rows of ONE column's stream -- via
// 64 lanes x 16B sequential. R7/R8/R10 all staged 16 scattered rows x 64B
// per instruction and all saturated at ~2.5-3 TB/s effective regardless of
// wave count or pipeline depth (the scattered-sector ceiling); the fill
// kernel does 6.9 TB/s contiguous. 16 insts stage one 4-step group for all
// 16 columns into a 16KB buffer; NBUF=3 ring, counted vmcnt(32) (never 0),
// 2 groups (~2000cy) of lead. In-flight 32KB/wave x 512 waves >> BW*latency.
//
// Anti-bank-conflict rotation (both-sides-or-neither, since DMA writes
// linearly): LDS phys float (col n, row slot s) = (sem + 4n) & 63, realized
// by pre-rotating the per-lane GLOBAL source address; the ds_read applies
// the same rotation. Per-lane end-clamp (row = min(row,Tn-1)) keeps true
// rows in their slots (a base clamp would shift the slot map and corrupt
// the record step).
__global__ __launch_bounds__(64) void crf_mfma(
    const float* __restrict__ emit,
    const int*   __restrict__ target,
    const int*   __restrict__ mask,
    const float* __restrict__ trans,
    const float* __restrict__ strans,
    const float* __restrict__ etrans,
    float*       __restrict__ out)
{
    __shared__ __align__(16) float sbuf[NBUF * 4096];   // 48 KB

    const int lane = threadIdx.x;
    const int n = lane & 15;          // column = segment
    const int g = lane >> 4;          // lane group
    const int b = blockIdx.x;
    const size_t ebase = (size_t)b * Tn * Nn;

    // ---- A fragments with k-map k = 32hh + 16*(j>>2) + 4g + (j&3)
    h8v A[4][2];
#pragma unroll
    for (int r = 0; r < 4; ++r)
#pragma unroll
        for (int hh = 0; hh < 2; ++hh) {
            h8v a;
#pragma unroll
            for (int j = 0; j < 8; ++j) {
                int kk = 32 * hh + 16 * (j >> 2) + 4 * g + (j & 3);
                a[j] = (_Float16)__expf(trans[kk * Nn + 16 * r + n]);
            }
            A[r][hh] = a;
        }

    // ---- len = popcount of prefix mask
    const int* mrow = mask + (size_t)b * Tn;
    int lsum = 0;
#pragma unroll
    for (int k = 0; k < Tn / Nn; ++k) lsum += mrow[k * Nn + lane];
#pragma unroll
    for (int off = 32; off >= 1; off >>= 1) lsum += __shfl_xor(lsum, off, 64);
    const int len = lsum;                       // in [512, 1024]

    // ---- per-column starts (all 16, for staging) + own bounds
    int startc[16];
#pragma unroll
    for (int c = 0; c < 16; ++c) {
        int a = ((c * len) >> 4) - BURN;
        startc[c] = (a < 1) ? 1 : a;
    }
    const int a0v   = (n * len) >> 4;
    const int start = startc[n];
    const int tendv = (((n + 1) * len) >> 4) - 1;
    const int maxk  = ((len + 15) >> 4) + BURN;

    // ---- end weights: only column 15 weights its final colsum
    float wsel[4][4];
#pragma unroll
    for (int r = 0; r < 4; ++r) {
        f4 ee = *(const f4*)(emit + ebase + (size_t)(len - 1) * Nn + 16 * r + 4 * g);
        f4 et = *(const f4*)(etrans + 16 * r + 4 * g);
#pragma unroll
        for (int c = 0; c < 4; ++c)
            wsel[r][c] = (n == 15) ? __expf(ee[c] + et[c]) : 1.0f;
    }

    // ---- U init (C/D layout: row = 16r + 4g + c, col n) = u_{start-1}
    float U[4][4];
#pragma unroll
    for (int r = 0; r < 4; ++r) {
        f4 st = *(const f4*)(strans + 16 * r + 4 * g);
#pragma unroll
        for (int c = 0; c < 4; ++c)
            U[r][c] = (start == 1) ? __expf(st[c]) : 1.0f;
    }

    int   S = 0;
    float L0 = 0.0f, contrib = 0.0f;

    // stage group jgrp (steps 4jgrp..4jgrp+3) into buffer bf:
    // 16 x 1KB-contiguous insts, one per column. Lane l covers row slot
    // l>>4, phys floats [4(l&15),+4) <- semantic floats (phys - 4cc) & 63.
    const int rowoff = lane >> 4;
    const int fb     = 4 * (lane & 15);
    auto stage = [&](int bf, int jgrp) {
        float* lb = sbuf + bf * 4096;
#pragma unroll
        for (int cc = 0; cc < 16; ++cc) {
            int row = startc[cc] + 4 * jgrp - 1 + rowoff;
            if (row > Tn - 1) row = Tn - 1;         // per-LANE clamp
            int fs = (fb + (64 - 4 * cc)) & 63;     // inverse rotation on src
            stage16(emit + ebase + (size_t)row * Nn + fs, lb + cc * 256);
        }
    };

    VMCNT(0);                       // isolate counting from prologue loads
    stage(0, 0); stage(1, 1);       // 32 outstanding
    __builtin_amdgcn_sched_barrier(0);

    const f4 zero4 = {0.f, 0.f, 0.f, 0.f};
    const int ngrp = (maxk + 3) >> 2;
    const int ro = (4 * g + 4 * n) & 63;            // read-side rotation
    int bc = 0, bs = 2;

    for (int jg = 0; jg < ngrp; ++jg) {
        stage(bs, jg + 2);          // 48 outstanding (tail groups: clamped re-reads, L2-hot)
        VMCNT(32);                  // oldest group (jg) landed; 2 groups in flight
        __builtin_amdgcn_sched_barrier(0);
        const float* cb = sbuf + bc * 4096 + n * 256;

#pragma unroll
        for (int q = 0; q < 4; ++q) {
            const int k = 4 * jg + q;

            const float* sb = cb + q * 64;
            f4 w0 = *(const f4*)(sb + ((ro +  0) & 63));
            f4 w1 = *(const f4*)(sb + ((ro + 16) & 63));
            f4 w2 = *(const f4*)(sb + ((ro + 32) & 63));
            f4 w3 = *(const f4*)(sb + ((ro + 48) & 63));
            float Wx[4][4];
#pragma unroll
            for (int c = 0; c < 4; ++c) {
                Wx[0][c] = __expf(w0[c]);
                Wx[1][c] = __expf(w1[c]);
                Wx[2][c] = __expf(w2[c]);
                Wx[3][c] = __expf(w3[c]);
            }

            // burn-in end: U = u_{a0v-1}; record L0, reset S (per-column k)
            bool br = n && ((start + k) == a0v);
            if (__any(br)) {
                float cs = 0.f;
#pragma unroll
                for (int r = 0; r < 4; ++r)
#pragma unroll
                    for (int c = 0; c < 4; ++c) cs += U[r][c];
                cs += __shfl_xor(cs, 16, 64);
                cs += __shfl_xor(cs, 32, 64);
                float l0v = __logf(cs);
                if (br) { L0 = l0v; S = 0; }
            }

            // per-column rescale: mx = col max -> mx*2^mk in [1,2)
            float m0 = fmaxf(fmaxf(U[0][0], U[0][1]), fmaxf(U[0][2], U[0][3]));
            float m1 = fmaxf(fmaxf(U[1][0], U[1][1]), fmaxf(U[1][2], U[1][3]));
            float m2 = fmaxf(fmaxf(U[2][0], U[2][1]), fmaxf(U[2][2], U[2][3]));
            float m3 = fmaxf(fmaxf(U[3][0], U[3][1]), fmaxf(U[3][2], U[3][3]));
            float mx = fmaxf(fmaxf(m0, m1), fmaxf(m2, m3));
            mx = fmaxf(mx, __shfl_xor(mx, 16, 64));
            mx = fmaxf(mx, __shfl_xor(mx, 32, 64));
            const int mk = 127 - ((__float_as_int(mx) >> 23) & 0xff);
            S += mk;
            const float sc2 = __int_as_float((127 + mk) << 23);   // 2^mk

            // p = U * 2^mk * W -> fp16, packed in-register as B (k-map above)
            float P_[4][4];
#pragma unroll
            for (int r = 0; r < 4; ++r)
#pragma unroll
                for (int c = 0; c < 4; ++c) P_[r][c] = U[r][c] * sc2 * Wx[r][c];

            pk2 c00 = __builtin_amdgcn_cvt_pkrtz(P_[0][0], P_[0][1]);
            pk2 c01 = __builtin_amdgcn_cvt_pkrtz(P_[0][2], P_[0][3]);
            pk2 c10 = __builtin_amdgcn_cvt_pkrtz(P_[1][0], P_[1][1]);
            pk2 c11 = __builtin_amdgcn_cvt_pkrtz(P_[1][2], P_[1][3]);
            pk2 c20 = __builtin_amdgcn_cvt_pkrtz(P_[2][0], P_[2][1]);
            pk2 c21 = __builtin_amdgcn_cvt_pkrtz(P_[2][2], P_[2][3]);
            pk2 c30 = __builtin_amdgcn_cvt_pkrtz(P_[3][0], P_[3][1]);
            pk2 c31 = __builtin_amdgcn_cvt_pkrtz(P_[3][2], P_[3][3]);
            pk4 b0lo = __builtin_shufflevector(c00, c01, 0, 1, 2, 3);
            pk4 b0hi = __builtin_shufflevector(c10, c11, 0, 1, 2, 3);
            pk4 b1lo = __builtin_shufflevector(c20, c21, 0, 1, 2, 3);
            pk4 b1hi = __builtin_shufflevector(c30, c31, 0, 1, 2, 3);
            pk8 b0p = __builtin_shufflevector(b0lo, b0hi, 0, 1, 2, 3, 4, 5, 6, 7);
            pk8 b1p = __builtin_shufflevector(b1lo, b1hi, 0, 1, 2, 3, 4, 5, 6, 7);
            h8v B0 = __builtin_bit_cast(h8v, b0p);
            h8v B1 = __builtin_bit_cast(h8v, b1p);

            // U' = Et x P  (8 MFMA)
#pragma unroll
            for (int r = 0; r < 4; ++r) {
                f4 acc = __builtin_amdgcn_mfma_f32_16x16x32_f16(A[r][0], B0, zero4, 0, 0, 0);
                acc     = __builtin_amdgcn_mfma_f32_16x16x32_f16(A[r][1], B1, acc,   0, 0, 0);
#pragma unroll
                for (int c = 0; c < 4; ++c) U[r][c] = acc[c];
            }

            // segment-end record (fires on ~2-3 iterations total)
            bool rec = (start + k) == tendv;
            if (__any(rec)) {
                float cs = 0.f;
#pragma unroll
                for (int r = 0; r < 4; ++r)
#pragma unroll
                    for (int c = 0; c < 4; ++c) cs = fmaf(U[r][c], wsel[r][c], cs);
                cs += __shfl_xor(cs, 16, 64);
                cs += __shfl_xor(cs, 32, 64);
                float lv = __logf(cs);
                if (rec) contrib = lv - (float)S * 0.6931471805599453f - L0;
            }
        }
        bc = (bc == NBUF - 1) ? 0 : bc + 1;
        bs = (bs == NBUF - 1) ? 0 : bs + 1;
    }
    VMCNT(0);   // drain tail stages (buffers dead)

    // 4 lanes per column hold identical contrib -> /4
    float tot = wave_sum(contrib) * 0.25f;

    // ---- gold-path score over the whole sequence (one wave per batch)
    const int* trow = target + (size_t)b * Tn;
    float sc = 0.0f;
#pragma unroll
    for (int k = 0; k < Tn / Nn; ++k) {
        int t = k * Nn + lane;
        if (t < len) {
            int gT = trow[t];
            sc += emit[ebase + (size_t)t * Nn + gT];
            if (t > 0) sc += trans[trow[t - 1] * Nn + gT];
        }
    }
    sc = wave_sum(sc);

    if (lane == 0) {
        sc += strans[trow[0]] + etrans[trow[len - 1]];
        atomicAdd(out, (tot - sc) * (1.0f / (float)Bn));
    }
}

extern "C" void kernel_launch(void* const* d_in, const int* in_sizes, int n_in,
                              void* d_out, int out_size, void* d_ws, size_t ws_size,
                              hipStream_t stream) {
    const float* emit   = (const float*)d_in[0];
    const int*   target = (const int*)d_in[1];
    const int*   mask   = (const int*)d_in[2];
    const float* trans  = (const float*)d_in[3];
    const float* strans = (const float*)d_in[4];
    const float* etrans = (const float*)d_in[5];
    float* out = (float*)d_out;

    (void)hipMemsetAsync(out, 0, sizeof(float), stream);
    crf_mfma<<<Bn, Nn, 0, stream>>>(emit, target, mask, trans, strans, etrans, out);
}

// Round 12
// 221.124 us; speedup vs baseline: 1.0804x; 1.0228x over previous
//
#include <hip/hip_runtime.h>

#define Bn 512
#define Tn 1024
#define Nn 64
#define WB 2      // waves per batch: 32 segments, wave h owns columns m = 16h+n
#define BURN 16   // burn-in steps (verified: R3 scalar + R6-R11 MFMA, absmax 0.0)
#define NBUF 2    // LDS group ring: 2 x 16KB (one 4-step group each); 32KB/block
                  // -> 4 blocks/CU resident (WB=2 grid = 4 waves/CU exactly)

typedef float    f4  __attribute__((ext_vector_type(4)));
typedef __fp16   pk2 __attribute__((ext_vector_type(2)));   // cvt_pkrtz result type
typedef __fp16   pk4 __attribute__((ext_vector_type(4)));
typedef __fp16   pk8 __attribute__((ext_vector_type(8)));
typedef _Float16 h8v __attribute__((ext_vector_type(8)));

typedef __attribute__((address_space(1))) void as1_void;
typedef __attribute__((address_space(3))) void as3_void;

// Direct global->LDS DMA, 16B/lane, LDS dest = uniform base + 16*lane.
__device__ __forceinline__ void stage16(const float* g, float* l) {
    __builtin_amdgcn_global_load_lds((as1_void*)(unsigned long long)g,
                                     (as3_void*)(unsigned long long)l, 16, 0, 0);
}
#define VMCNT(N) asm volatile("s_waitcnt vmcnt(" #N ")" ::: "memory")

__device__ __forceinline__ float wave_sum(float v) {
#pragma unroll
    for (int off = 32; off >= 1; off >>= 1) v += __shfl_xor(v, off, 64);
    return v;
}

// One wave = 16 of the 32 segments of batch b (m = 16h+n); WB=2 waves/batch.
// U' = E^T diag-scaled P, 8 mfma/step, B packed in-register (k-map == C/D
// layout; A uses same k-map -> contraction invariant). Staging is the
// R11-verified coalesced-by-column global_load_lds (1KB contiguous/inst,
// source-rotated against bank conflicts, per-LANE row clamp) with counted
// vmcnt. CHANGE vs R11: waves 512 -> 1024. Cross-round normalization showed
// the DMA path runs at a fixed ~4 GB/s PER WAVE when coalesced (R11) vs
// 1.5 GB/s scattered (R8); total BW scales with wave count, and R11 had 4x
// fewer waves than R8. This round combines coalesced staging WITH more
// waves. NBUF=2 (not 3) so 4 blocks/CU fit LDS; lead = 1 group = 4 steps
// (~2000cy) > HBM latency (~900cy).
__global__ __launch_bounds__(64) void crf_mfma(
    const float* __restrict__ emit,
    const int*   __restrict__ target,
    const int*   __restrict__ mask,
    const float* __restrict__ trans,
    const float* __restrict__ strans,
    const float* __restrict__ etrans,
    float*       __restrict__ out)
{
    __shared__ __align__(16) float sbuf[NBUF * 4096];   // 32 KB

    const int lane = threadIdx.x;
    const int n = lane & 15;          // column within this wave's MFMA
    const int g = lane >> 4;          // lane group
    const int b = blockIdx.x & (Bn - 1);
    const int h = blockIdx.x >> 9;    // 0..1
    const int m = 16 * h + n;         // global segment id, 0..31
    const size_t ebase = (size_t)b * Tn * Nn;

    // ---- A fragments with k-map k = 32hh + 16*(j>>2) + 4g + (j&3)
    h8v A[4][2];
#pragma unroll
    for (int r = 0; r < 4; ++r)
#pragma unroll
        for (int hh = 0; hh < 2; ++hh) {
            h8v a;
#pragma unroll
            for (int j = 0; j < 8; ++j) {
                int kk = 32 * hh + 16 * (j >> 2) + 4 * g + (j & 3);
                a[j] = (_Float16)__expf(trans[kk * Nn + 16 * r + n]);
            }
            A[r][hh] = a;
        }

    // ---- len = popcount of prefix mask
    const int* mrow = mask + (size_t)b * Tn;
    int lsum = 0;
#pragma unroll
    for (int k = 0; k < Tn / Nn; ++k) lsum += mrow[k * Nn + lane];
#pragma unroll
    for (int off = 32; off >= 1; off >>= 1) lsum += __shfl_xor(lsum, off, 64);
    const int len = lsum;                       // in [512, 1024]

    // ---- per-column starts for this wave's 16 columns (global ids 16h+cc)
    int startc[16];
#pragma unroll
    for (int cc = 0; cc < 16; ++cc) {
        int a = (((16 * h + cc) * len) >> 5) - BURN;
        startc[cc] = (a < 1) ? 1 : a;
    }
    const int a0v   = (m * len) >> 5;
    const int start = startc[n];
    const int tendv = (((m + 1) * len) >> 5) - 1;
    const int maxk  = ((len + 31) >> 5) + BURN;

    // ---- end weights: only global segment 31 weights its final colsum
    float wsel[4][4];
#pragma unroll
    for (int r = 0; r < 4; ++r) {
        f4 ee = *(const f4*)(emit + ebase + (size_t)(len - 1) * Nn + 16 * r + 4 * g);
        f4 et = *(const f4*)(etrans + 16 * r + 4 * g);
#pragma unroll
        for (int c = 0; c < 4; ++c)
            wsel[r][c] = (m == 31) ? __expf(ee[c] + et[c]) : 1.0f;
    }

    // ---- U init (C/D layout: row = 16r + 4g + c, col n) = u_{start-1}
    // start==1 (m==0 or clamped early segment): exact prefix from u_0.
    float U[4][4];
#pragma unroll
    for (int r = 0; r < 4; ++r) {
        f4 st = *(const f4*)(strans + 16 * r + 4 * g);
#pragma unroll
        for (int c = 0; c < 4; ++c)
            U[r][c] = (start == 1) ? __expf(st[c]) : 1.0f;
    }

    int   S = 0;
    float L0 = 0.0f, contrib = 0.0f;

    // stage group jgrp (steps 4jgrp..4jgrp+3) into buffer bf:
    // 16 x 1KB-contiguous insts, one per column. Lane l covers row slot
    // l>>4, phys floats [4(l&15),+4) <- semantic floats (phys - 4cc) & 63.
    const int rowoff = lane >> 4;
    const int fb     = 4 * (lane & 15);
    auto stage = [&](int bf, int jgrp) {
        float* lb = sbuf + bf * 4096;
#pragma unroll
        for (int cc = 0; cc < 16; ++cc) {
            int row = startc[cc] + 4 * jgrp - 1 + rowoff;
            if (row > Tn - 1) row = Tn - 1;         // per-LANE clamp
            int fs = (fb + (64 - 4 * cc)) & 63;     // inverse rotation on src
            stage16(emit + ebase + (size_t)row * Nn + fs, lb + cc * 256);
        }
    };

    VMCNT(0);                       // isolate counting from prologue loads
    stage(0, 0);                    // 16 outstanding
    __builtin_amdgcn_sched_barrier(0);

    const f4 zero4 = {0.f, 0.f, 0.f, 0.f};
    const int ngrp = (maxk + 3) >> 2;
    const int ro = (4 * g + 4 * n) & 63;            // read-side rotation

    for (int jg = 0; jg < ngrp; ++jg) {
        stage((jg + 1) & 1, jg + 1);    // 32 outstanding (last iter: clamped re-reads, L2-hot)
        VMCNT(16);                      // group jg landed; 1 group in flight
        __builtin_amdgcn_sched_barrier(0);
        const float* cb = sbuf + (jg & 1) * 4096 + n * 256;

#pragma unroll
        for (int q = 0; q < 4; ++q) {
            const int k = 4 * jg + q;

            const float* sb = cb + q * 64;
            f4 w0 = *(const f4*)(sb + ((ro +  0) & 63));
            f4 w1 = *(const f4*)(sb + ((ro + 16) & 63));
            f4 w2 = *(const f4*)(sb + ((ro + 32) & 63));
            f4 w3 = *(const f4*)(sb + ((ro + 48) & 63));
            float Wx[4][4];
#pragma unroll
            for (int c = 0; c < 4; ++c) {
                Wx[0][c] = __expf(w0[c]);
                Wx[1][c] = __expf(w1[c]);
                Wx[2][c] = __expf(w2[c]);
                Wx[3][c] = __expf(w3[c]);
            }

            // burn-in end: U = u_{a0v-1}; record L0, reset S (per-column k)
            bool br = m && ((start + k) == a0v);
            if (__any(br)) {
                float cs = 0.f;
#pragma unroll
                for (int r = 0; r < 4; ++r)
#pragma unroll
                    for (int c = 0; c < 4; ++c) cs += U[r][c];
                cs += __shfl_xor(cs, 16, 64);
                cs += __shfl_xor(cs, 32, 64);
                float l0v = __logf(cs);
                if (br) { L0 = l0v; S = 0; }
            }

            // per-column rescale: mx = col max -> mx*2^mk in [1,2)
            float m0 = fmaxf(fmaxf(U[0][0], U[0][1]), fmaxf(U[0][2], U[0][3]));
            float m1 = fmaxf(fmaxf(U[1][0], U[1][1]), fmaxf(U[1][2], U[1][3]));
            float m2 = fmaxf(fmaxf(U[2][0], U[2][1]), fmaxf(U[2][2], U[2][3]));
            float m3 = fmaxf(fmaxf(U[3][0], U[3][1]), fmaxf(U[3][2], U[3][3]));
            float mx = fmaxf(fmaxf(m0, m1), fmaxf(m2, m3));
            mx = fmaxf(mx, __shfl_xor(mx, 16, 64));
            mx = fmaxf(mx, __shfl_xor(mx, 32, 64));
            const int mk = 127 - ((__float_as_int(mx) >> 23) & 0xff);
            S += mk;
            const float sc2 = __int_as_float((127 + mk) << 23);   // 2^mk

            // p = U * 2^mk * W -> fp16, packed in-register as B (k-map above)
            float P_[4][4];
#pragma unroll
            for (int r = 0; r < 4; ++r)
#pragma unroll
                for (int c = 0; c < 4; ++c) P_[r][c] = U[r][c] * sc2 * Wx[r][c];

            pk2 c00 = __builtin_amdgcn_cvt_pkrtz(P_[0][0], P_[0][1]);
            pk2 c01 = __builtin_amdgcn_cvt_pkrtz(P_[0][2], P_[0][3]);
            pk2 c10 = __builtin_amdgcn_cvt_pkrtz(P_[1][0], P_[1][1]);
            pk2 c11 = __builtin_amdgcn_cvt_pkrtz(P_[1][2], P_[1][3]);
            pk2 c20 = __builtin_amdgcn_cvt_pkrtz(P_[2][0], P_[2][1]);
            pk2 c21 = __builtin_amdgcn_cvt_pkrtz(P_[2][2], P_[2][3]);
            pk2 c30 = __builtin_amdgcn_cvt_pkrtz(P_[3][0], P_[3][1]);
            pk2 c31 = __builtin_amdgcn_cvt_pkrtz(P_[3][2], P_[3][3]);
            pk4 b0lo = __builtin_shufflevector(c00, c01, 0, 1, 2, 3);
            pk4 b0hi = __builtin_shufflevector(c10, c11, 0, 1, 2, 3);
            pk4 b1lo = __builtin_shufflevector(c20, c21, 0, 1, 2, 3);
            pk4 b1hi = __builtin_shufflevector(c30, c31, 0, 1, 2, 3);
            pk8 b0p = __builtin_shufflevector(b0lo, b0hi, 0, 1, 2, 3, 4, 5, 6, 7);
            pk8 b1p = __builtin_shufflevector(b1lo, b1hi, 0, 1, 2, 3, 4, 5, 6, 7);
            h8v B0 = __builtin_bit_cast(h8v, b0p);
            h8v B1 = __builtin_bit_cast(h8v, b1p);

            // U' = Et x P  (8 MFMA)
#pragma unroll
            for (int r = 0; r < 4; ++r) {
                f4 acc = __builtin_amdgcn_mfma_f32_16x16x32_f16(A[r][0], B0, zero4, 0, 0, 0);
                acc     = __builtin_amdgcn_mfma_f32_16x16x32_f16(A[r][1], B1, acc,   0, 0, 0);
#pragma unroll
                for (int c = 0; c < 4; ++c) U[r][c] = acc[c];
            }

            // segment-end record (fires on ~2-3 iterations total)
            bool rec = (start + k) == tendv;
            if (__any(rec)) {
                float cs = 0.f;
#pragma unroll
                for (int r = 0; r < 4; ++r)
#pragma unroll
                    for (int c = 0; c < 4; ++c) cs = fmaf(U[r][c], wsel[r][c], cs);
                cs += __shfl_xor(cs, 16, 64);
                cs += __shfl_xor(cs, 32, 64);
                float lv = __logf(cs);
                if (rec) contrib = lv - (float)S * 0.6931471805599453f - L0;
            }
        }
    }
    VMCNT(0);   // drain tail stages (buffers dead)

    // 4 lanes per column hold identical contrib -> /4
    float tot = wave_sum(contrib) * 0.25f;

    // ---- gold-path score: computed once per batch, by wave h==0
    float sc = 0.0f;
    const int* trow = target + (size_t)b * Tn;
    if (h == 0) {
#pragma unroll
        for (int k = 0; k < Tn / Nn; ++k) {
            int t = k * Nn + lane;
            if (t < len) {
                int gT = trow[t];
                sc += emit[ebase + (size_t)t * Nn + gT];
                if (t > 0) sc += trans[trow[t - 1] * Nn + gT];
            }
        }
        sc = wave_sum(sc);
    }

    if (lane == 0) {
        float add = tot;
        if (h == 0) add -= sc + strans[trow[0]] + etrans[trow[len - 1]];
        atomicAdd(out, add * (1.0f / (float)Bn));
    }
}

extern "C" void kernel_launch(void* const* d_in, const int* in_sizes, int n_in,
                              void* d_out, int out_size, void* d_ws, size_t ws_size,
                              hipStream_t stream) {
    const float* emit   = (const float*)d_in[0];
    const int*   target = (const int*)d_in[1];
    const int*   mask   = (const int*)d_in[2];
    const float* trans  = (const float*)d_in[3];
    const float* strans = (const float*)d_in[4];
    const float* etrans = (const float*)d_in[5];
    float* out = (float*)d_out;

    (void)hipMemsetAsync(out, 0, sizeof(float), stream);
    crf_mfma<<<Bn * WB, Nn, 0, stream>>>(emit, target, mask, trans, strans, etrans, out);
}